// Round 3
// baseline (1557.599 us; speedup 1.0000x reference)
//
#include <hip/hip_runtime.h>

#define IN_F   4096
#define OUT_F  4096
#define N_TOK  8192
#define NW     (OUT_F * IN_F)          // 16777216 weight elements
#define SEL_TARGET 8388608u            // 0-based ascending index of kth (= NW - MAX_ITER)
#define CAND_CAP (1u << 20)            // 1M keys (expected ~65K)

typedef unsigned int  u32;
typedef unsigned short u16;

typedef __bf16 bf16x8 __attribute__((ext_vector_type(8)));
typedef float  f32x4  __attribute__((ext_vector_type(4)));

// ---------- helpers ----------
__device__ inline u16 f2bf_rne(float f) {
    u32 u = __float_as_uint(f);
    u32 r = (u + 0x7fffu + ((u >> 16) & 1u)) >> 16;
    return (u16)r;
}

// ---------- selection: pass 1 — 14-bit MSB histogram (16384 bins) ----------
__global__ __launch_bounds__(1024) void hist1_kernel(const uint4* __restrict__ wb,
                                                     u32* __restrict__ hist) {
    __shared__ u32 lh[16384];
    for (int i = threadIdx.x; i < 16384; i += 1024) lh[i] = 0;
    __syncthreads();

    const int nvec = NW / 4;
    const int stride = gridDim.x * 1024;
    for (int i = blockIdx.x * 1024 + threadIdx.x; i < nvec; i += stride) {
        uint4 v = wb[i];
        atomicAdd(&lh[(v.x & 0x7fffffffu) >> 17], 1u);
        atomicAdd(&lh[(v.y & 0x7fffffffu) >> 17], 1u);
        atomicAdd(&lh[(v.z & 0x7fffffffu) >> 17], 1u);
        atomicAdd(&lh[(v.w & 0x7fffffffu) >> 17], 1u);
    }
    __syncthreads();
    for (int i = threadIdx.x; i < 16384; i += 1024)
        if (lh[i]) atomicAdd(&hist[i], lh[i]);
}

// ---------- selection: find bin in 16384-bin histogram ----------
__global__ __launch_bounds__(1024) void find1_kernel(const u32* __restrict__ hist,
                                                     u32* __restrict__ scal) {
    __shared__ u32 part[1024];
    const int t = threadIdx.x;
    u32 loc[16];
    u32 s = 0;
    #pragma unroll
    for (int i = 0; i < 16; i++) { loc[i] = hist[t * 16 + i]; s += loc[i]; }
    part[t] = s;
    __syncthreads();
    #pragma unroll
    for (int off = 1; off < 1024; off <<= 1) {
        u32 v = (t >= off) ? part[t - off] : 0u;
        __syncthreads();
        part[t] += v;
        __syncthreads();
    }
    u32 cum = (t == 0) ? 0u : part[t - 1];
    const u32 target = SEL_TARGET;
    #pragma unroll
    for (int i = 0; i < 16; i++) {
        u32 h = loc[i];
        if (target >= cum && target < cum + h) {
            scal[0] = (u32)(t * 16 + i);   // 14-bit prefix
            scal[1] = target - cum;        // remaining rank within bin
        }
        cum += h;
    }
}

// ---------- selection: pass 2 — compact candidates of the chosen bin ----------
__global__ void compact_kernel(const uint4* __restrict__ wb,
                               u32* __restrict__ cand,
                               u32* __restrict__ scal) {
    const u32 pfx = scal[0];
    const int nvec = NW / 4;
    const int stride = gridDim.x * blockDim.x;
    for (int i = blockIdx.x * blockDim.x + threadIdx.x; i < nvec; i += stride) {
        uint4 v = wb[i];
        u32 k[4] = {v.x & 0x7fffffffu, v.y & 0x7fffffffu,
                    v.z & 0x7fffffffu, v.w & 0x7fffffffu};
        #pragma unroll
        for (int j = 0; j < 4; j++) {
            if ((k[j] >> 17) == pfx) {
                u32 idx = atomicAdd(&scal[3], 1u);
                if (idx < CAND_CAP) cand[idx] = k[j];
            }
        }
    }
}

// ---------- selection: pass 3 — select within candidates (17 remaining bits) ----------
__global__ __launch_bounds__(1024) void select3_kernel(const u32* __restrict__ cand,
                                                       u32* __restrict__ scal) {
    __shared__ u32 h2[2048];
    __shared__ u32 part[1024];
    __shared__ u32 h3[64];
    __shared__ u32 sh[2];
    const int t = threadIdx.x;
    const u32 n = min(scal[3], CAND_CAP);
    const u32 tgt = scal[1];

    for (int i = t; i < 2048; i += 1024) h2[i] = 0;
    __syncthreads();
    for (u32 i = t; i < n; i += 1024)
        atomicAdd(&h2[(cand[i] >> 6) & 2047u], 1u);
    __syncthreads();

    u32 a0 = h2[t * 2], a1 = h2[t * 2 + 1];
    part[t] = a0 + a1;
    __syncthreads();
    #pragma unroll
    for (int off = 1; off < 1024; off <<= 1) {
        u32 v = (t >= off) ? part[t - off] : 0u;
        __syncthreads();
        part[t] += v;
        __syncthreads();
    }
    u32 cum = (t == 0) ? 0u : part[t - 1];
    if (tgt >= cum && tgt < cum + a0) { sh[0] = (u32)(t * 2);     sh[1] = tgt - cum; }
    cum += a0;
    if (tgt >= cum && tgt < cum + a1) { sh[0] = (u32)(t * 2 + 1); sh[1] = tgt - cum; }
    __syncthreads();
    const u32 b2 = sh[0], tgt2 = sh[1];

    if (t < 64) h3[t] = 0;
    __syncthreads();
    for (u32 i = t; i < n; i += 1024) {
        u32 k = cand[i];
        if (((k >> 6) & 2047u) == b2) atomicAdd(&h3[k & 63u], 1u);
    }
    __syncthreads();
    if (t == 0) {
        u32 c = 0;
        #pragma unroll
        for (int b = 0; b < 64; b++) {
            u32 h = h3[b];
            if (tgt2 >= c && tgt2 < c + h)
                scal[2] = (scal[0] << 17) | (b2 << 6) | (u32)b;   // kth |w| bit pattern
            c += h;
        }
    }
}

// ---------- mask + f32->bf16 conversion ----------
__global__ void convert_w_kernel(const uint4* __restrict__ wb,
                                 u16* __restrict__ w16,
                                 const u32* __restrict__ scal) {
    const u32 kth = scal[2];
    const int nvec = NW / 4;
    const int stride = gridDim.x * blockDim.x;
    for (int i = blockIdx.x * blockDim.x + threadIdx.x; i < nvec; i += stride) {
        uint4 v = wb[i];
        ushort4 o;
        o.x = ((v.x & 0x7fffffffu) >= kth) ? f2bf_rne(__uint_as_float(v.x)) : (u16)0;
        o.y = ((v.y & 0x7fffffffu) >= kth) ? f2bf_rne(__uint_as_float(v.y)) : (u16)0;
        o.z = ((v.z & 0x7fffffffu) >= kth) ? f2bf_rne(__uint_as_float(v.z)) : (u16)0;
        o.w = ((v.w & 0x7fffffffu) >= kth) ? f2bf_rne(__uint_as_float(v.w)) : (u16)0;
        *(ushort4*)&w16[(size_t)i * 4] = o;
    }
}

__global__ void convert_x_kernel(const float4* __restrict__ xb,
                                 u16* __restrict__ x16) {
    const int nvec = (N_TOK * IN_F) / 4;
    const int stride = gridDim.x * blockDim.x;
    for (int i = blockIdx.x * blockDim.x + threadIdx.x; i < nvec; i += stride) {
        float4 v = xb[i];
        ushort4 o;
        o.x = f2bf_rne(v.x);
        o.y = f2bf_rne(v.y);
        o.z = f2bf_rne(v.z);
        o.w = f2bf_rne(v.w);
        *(ushort4*)&x16[(size_t)i * 4] = o;
    }
}

// ---------- 256x256 8-phase bf16 MFMA GEMM (m201-style template) ----------
// C[t,o] = sum_k A[t,k] * B[o,k] + bias[o];  A = x16 [8192][4096], B = w16 [4096][4096]
#define BK 64
#define NT (IN_F / BK)   // 64 K-tiles

#define ASLOT(buf, ks) (((buf) * 2 + (ks)) * 8192)
#define BSLOT(buf, ks) (32768 + ((buf) * 2 + (ks)) * 8192)

#define VMCNT(n) asm volatile("s_waitcnt vmcnt(" #n ")" ::: "memory")
#define LGKM0    asm volatile("s_waitcnt lgkmcnt(0)" ::: "memory")
#define SB0      __builtin_amdgcn_sched_barrier(0)
#define BARR()   __builtin_amdgcn_s_barrier()

__global__ __launch_bounds__(512, 2) void gemm8p(
    const u16* __restrict__ A,
    const u16* __restrict__ B,
    const float* __restrict__ bias,
    float* __restrict__ C) {
    __shared__ u16 lds[65536];   // 128 KiB

    const int tid  = threadIdx.x;
    const int lane = tid & 63;
    const int ln15 = lane & 15;
    const int l16  = lane >> 4;
    const int wv   = tid >> 6;       // 0..7
    const int wr   = wv >> 2;        // 0..1  (M)
    const int wc   = wv & 3;         // 0..3  (N)
    const int wrow = wr * 128;
    const int wcol = wc * 64;

    const int bid = blockIdx.x;
    const int swz = (bid & 7) * 64 + (bid >> 3);
    const int by  = swz >> 4;        // 0..31
    const int bx  = swz & 15;        // 0..15
    const int arow = by * 256;
    const int brow = bx * 256;

    f32x4 acc[8][4];
    #pragma unroll
    for (int m = 0; m < 8; m++)
        #pragma unroll
        for (int n = 0; n < 4; n++)
            acc[m][n] = {0.f, 0.f, 0.f, 0.f};

    #define STAGE(G, rowbase, kt, ks, slot) do {                                        \
        _Pragma("unroll")                                                               \
        for (int i_ = 0; i_ < 2; i_++) {                                                \
            int q_  = tid + i_ * 512;                                                   \
            int r_  = q_ >> 2;                                                          \
            int cs_ = (q_ & 3) ^ ((r_ >> 1) & 3);                                       \
            const u16* src_ = (G) + (size_t)((rowbase) + r_) * IN_F                     \
                              + (kt) * BK + (ks) * 32 + cs_ * 8;                        \
            __builtin_amdgcn_global_load_lds(                                           \
                (const __attribute__((address_space(1))) unsigned int*)src_,            \
                (__attribute__((address_space(3))) unsigned int*)&lds[(slot) + q_ * 8], \
                16, 0, 0);                                                              \
        } } while (0)

    #define READ_A(mh, ks, buf) do {                                                    \
        _Pragma("unroll")                                                               \
        for (int i_ = 0; i_ < 4; i_++) {                                                \
            int row_ = wrow + ((mh) * 4 + i_) * 16 + ln15;                              \
            int cc_  = l16 ^ ((row_ >> 1) & 3);                                         \
            aF[i_] = *(const bf16x8*)&lds[ASLOT(buf, ks) + row_ * 32 + cc_ * 8];        \
        } } while (0)

    #define READ_B(ks, buf) do {                                                       \
        _Pragma("unroll")                                                               \
        for (int i_ = 0; i_ < 4; i_++) {                                                \
            int row_ = wcol + i_ * 16 + ln15;                                           \
            int cc_  = l16 ^ ((row_ >> 1) & 3);                                         \
            bF[i_] = *(const bf16x8*)&lds[BSLOT(buf, ks) + row_ * 32 + cc_ * 8];        \
        } } while (0)

    #define MFMAQ(mh) do {                                                              \
        __builtin_amdgcn_s_setprio(1);                                                  \
        _Pragma("unroll")                                                               \
        for (int i_ = 0; i_ < 4; i_++)                                                  \
            _Pragma("unroll")                                                           \
            for (int n_ = 0; n_ < 4; n_++)                                              \
                acc[(mh) * 4 + i_][n_] = __builtin_amdgcn_mfma_f32_16x16x32_bf16(       \
                    aF[i_], bF[n_], acc[(mh) * 4 + i_][n_], 0, 0, 0);                   \
        __builtin_amdgcn_s_setprio(0);                                                  \
    } while (0)

    STAGE(B, brow, 0, 0, BSLOT(0, 0));
    STAGE(A, arow, 0, 0, ASLOT(0, 0));
    STAGE(B, brow, 0, 1, BSLOT(0, 1));
    STAGE(A, arow, 0, 1, ASLOT(0, 1));
    VMCNT(4);
    STAGE(B, brow, 1, 0, BSLOT(1, 0));
    STAGE(A, arow, 1, 0, ASLOT(1, 0));
    STAGE(B, brow, 1, 1, BSLOT(1, 1));
    VMCNT(6);
    BARR();

    bf16x8 aF[4], bF[4];

    #pragma unroll 1
    for (int it = 0; it < NT / 2; it++) {
        const int t0 = 2 * it;
        const int ka = t0 + 1;
        const int kb = (t0 + 2 < NT) ? t0 + 2 : NT - 1;
        const int kc = (t0 + 3 < NT) ? t0 + 3 : NT - 1;

        // ---- tile t0 (buf 0) ----
        READ_A(0, 0, 0); READ_B(0, 0);
        STAGE(A, arow, ka, 1, ASLOT(1, 1));
        BARR(); LGKM0; SB0; MFMAQ(0); SB0; BARR();
        READ_A(1, 0, 0);
        STAGE(B, brow, kb, 0, BSLOT(0, 0));
        BARR(); LGKM0; SB0; MFMAQ(1); SB0; BARR();
        READ_A(0, 1, 0); READ_B(1, 0);
        STAGE(A, arow, kb, 0, ASLOT(0, 0));
        BARR(); LGKM0; SB0; MFMAQ(0); SB0; BARR();
        READ_A(1, 1, 0);
        STAGE(B, brow, kb, 1, BSLOT(0, 1));
        VMCNT(6);
        BARR(); LGKM0; SB0; MFMAQ(1); SB0; BARR();

        // ---- tile t0+1 (buf 1) ----
        READ_A(0, 0, 1); READ_B(0, 1);
        STAGE(A, arow, kb, 1, ASLOT(0, 1));
        BARR(); LGKM0; SB0; MFMAQ(0); SB0; BARR();
        READ_A(1, 0, 1);
        STAGE(B, brow, kc, 0, BSLOT(1, 0));
        BARR(); LGKM0; SB0; MFMAQ(1); SB0; BARR();
        READ_A(0, 1, 1); READ_B(1, 1);
        STAGE(A, arow, kc, 0, ASLOT(1, 0));
        BARR(); LGKM0; SB0; MFMAQ(0); SB0; BARR();
        READ_A(1, 1, 1);
        STAGE(B, brow, kc, 1, BSLOT(1, 1));
        VMCNT(6);
        BARR(); LGKM0; SB0; MFMAQ(1); SB0; BARR();
    }
    VMCNT(0);

    const int cr = l16 * 4;
    #pragma unroll
    for (int n = 0; n < 4; n++) {
        int col = brow + wcol + n * 16 + ln15;
        float bv = bias[col];
        #pragma unroll
        for (int m = 0; m < 8; m++) {
            int r0 = arow + wrow + m * 16 + cr;
            #pragma unroll
            for (int j = 0; j < 4; j++) {
                C[(size_t)(r0 + j) * OUT_F + col] = acc[m][n][j] + bv;
            }
        }
    }
}

// ---------- launch ----------
extern "C" void kernel_launch(void* const* d_in, const int* in_sizes, int n_in,
                              void* d_out, int out_size, void* d_ws, size_t ws_size,
                              hipStream_t stream) {
    const float* x    = (const float*)d_in[0];
    const float* w    = (const float*)d_in[1];
    const float* bias = (const float*)d_in[2];
    float* out = (float*)d_out;

    char* ws = (char*)d_ws;
    u32* scal  = (u32*)(ws + 0);                             // 16 u32: [0]=prefix [1]=rem [2]=kth [3]=cand count
    u16* w16   = (u16*)(ws + 65536);                         // 33.5 MB
    u16* x16   = (u16*)(ws + 65536 + (size_t)NW * 2);        // 67 MB
    // hist + cand overlap the x16 region (consumed before convert_x writes it)
    u32* hist16k = (u32*)x16;                                // 64 KB
    u32* cand    = (u32*)((char*)x16 + 131072);              // 4 MB

    hipMemsetAsync(scal, 0, 64, stream);
    hipMemsetAsync(hist16k, 0, 65536, stream);

    hist1_kernel<<<256, 1024, 0, stream>>>((const uint4*)w, hist16k);
    find1_kernel<<<1, 1024, 0, stream>>>(hist16k, scal);
    compact_kernel<<<2048, 256, 0, stream>>>((const uint4*)w, cand, scal);
    select3_kernel<<<1, 1024, 0, stream>>>(cand, scal);

    convert_w_kernel<<<2048, 256, 0, stream>>>((const uint4*)w, w16, scal);
    convert_x_kernel<<<2048, 256, 0, stream>>>((const float4*)x, x16);

    gemm8p<<<512, 512, 0, stream>>>(x16, w16, bias, out);
}

// Round 4
// 423.115 us; speedup vs baseline: 3.6813x; 3.6813x over previous
//
#include <hip/hip_runtime.h>

#define IN_F   4096
#define OUT_F  4096
#define N_TOK  8192
#define NW     (OUT_F * IN_F)          // 16777216 weight elements
#define SEL_TARGET 8388608u            // 0-based ascending index of kth (= NW - MAX_ITER)
#define CAND_CAP (1u << 20)            // 1M keys (expected ~65K)

typedef unsigned int  u32;
typedef unsigned short u16;

typedef __bf16 bf16x8 __attribute__((ext_vector_type(8)));
typedef float  f32x4  __attribute__((ext_vector_type(4)));

// ---------- helpers ----------
__device__ inline u16 f2bf_rne(float f) {
    u32 u = __float_as_uint(f);
    u32 r = (u + 0x7fffu + ((u >> 16) & 1u)) >> 16;
    return (u16)r;
}

// ---------- selection: pass 1 — 14-bit MSB histogram (16384 bins) ----------
__global__ __launch_bounds__(1024) void hist1_kernel(const uint4* __restrict__ wb,
                                                     u32* __restrict__ hist) {
    __shared__ u32 lh[16384];
    for (int i = threadIdx.x; i < 16384; i += 1024) lh[i] = 0;
    __syncthreads();

    const int nvec = NW / 4;
    const int stride = gridDim.x * 1024;
    for (int i = blockIdx.x * 1024 + threadIdx.x; i < nvec; i += stride) {
        uint4 v = wb[i];
        atomicAdd(&lh[(v.x & 0x7fffffffu) >> 17], 1u);
        atomicAdd(&lh[(v.y & 0x7fffffffu) >> 17], 1u);
        atomicAdd(&lh[(v.z & 0x7fffffffu) >> 17], 1u);
        atomicAdd(&lh[(v.w & 0x7fffffffu) >> 17], 1u);
    }
    __syncthreads();
    for (int i = threadIdx.x; i < 16384; i += 1024)
        if (lh[i]) atomicAdd(&hist[i], lh[i]);
}

// ---------- selection: find bin in 16384-bin histogram ----------
__global__ __launch_bounds__(1024) void find1_kernel(const u32* __restrict__ hist,
                                                     u32* __restrict__ scal) {
    __shared__ u32 part[1024];
    const int t = threadIdx.x;
    u32 loc[16];
    u32 s = 0;
    #pragma unroll
    for (int i = 0; i < 16; i++) { loc[i] = hist[t * 16 + i]; s += loc[i]; }
    part[t] = s;
    __syncthreads();
    #pragma unroll
    for (int off = 1; off < 1024; off <<= 1) {
        u32 v = (t >= off) ? part[t - off] : 0u;
        __syncthreads();
        part[t] += v;
        __syncthreads();
    }
    u32 cum = (t == 0) ? 0u : part[t - 1];
    const u32 target = SEL_TARGET;
    #pragma unroll
    for (int i = 0; i < 16; i++) {
        u32 h = loc[i];
        if (target >= cum && target < cum + h) {
            scal[0] = (u32)(t * 16 + i);   // 14-bit prefix
            scal[1] = target - cum;        // remaining rank within bin
        }
        cum += h;
    }
}

// ---------- selection: pass 2 — compact candidates (per-block LDS aggregation) ----------
// Each block owns 1024 uint4 = 4096 elements; LDS buffer sized to worst case.
__global__ __launch_bounds__(256) void compact_kernel(const uint4* __restrict__ wb,
                                                      u32* __restrict__ cand,
                                                      u32* __restrict__ scal) {
    __shared__ u32 lbuf[4096];
    __shared__ u32 lcnt;
    __shared__ u32 gbase;
    if (threadIdx.x == 0) lcnt = 0;
    const u32 pfx = scal[0];
    __syncthreads();

    const int base = blockIdx.x * 1024;
    #pragma unroll
    for (int j = 0; j < 4; j++) {
        uint4 v = wb[base + threadIdx.x + j * 256];
        u32 k[4] = {v.x & 0x7fffffffu, v.y & 0x7fffffffu,
                    v.z & 0x7fffffffu, v.w & 0x7fffffffu};
        #pragma unroll
        for (int e = 0; e < 4; e++) {
            if ((k[e] >> 17) == pfx) {
                u32 idx = atomicAdd(&lcnt, 1u);   // LDS atomic — cheap
                lbuf[idx] = k[e];
            }
        }
    }
    __syncthreads();
    if (threadIdx.x == 0) gbase = atomicAdd(&scal[3], lcnt);   // 1 global atomic / block
    __syncthreads();
    const u32 n = lcnt, gb = gbase;
    for (u32 i = threadIdx.x; i < n; i += 256)
        if (gb + i < CAND_CAP) cand[gb + i] = lbuf[i];
}

// ---------- selection: pass 3 — select within candidates (17 remaining bits) ----------
__global__ __launch_bounds__(1024) void select3_kernel(const u32* __restrict__ cand,
                                                       u32* __restrict__ scal) {
    __shared__ u32 h2[2048];
    __shared__ u32 part[1024];
    __shared__ u32 h3[64];
    __shared__ u32 sh[2];
    const int t = threadIdx.x;
    const u32 n = min(scal[3], CAND_CAP);
    const u32 tgt = scal[1];

    for (int i = t; i < 2048; i += 1024) h2[i] = 0;
    __syncthreads();
    for (u32 i = t; i < n; i += 1024)
        atomicAdd(&h2[(cand[i] >> 6) & 2047u], 1u);
    __syncthreads();

    u32 a0 = h2[t * 2], a1 = h2[t * 2 + 1];
    part[t] = a0 + a1;
    __syncthreads();
    #pragma unroll
    for (int off = 1; off < 1024; off <<= 1) {
        u32 v = (t >= off) ? part[t - off] : 0u;
        __syncthreads();
        part[t] += v;
        __syncthreads();
    }
    u32 cum = (t == 0) ? 0u : part[t - 1];
    if (tgt >= cum && tgt < cum + a0) { sh[0] = (u32)(t * 2);     sh[1] = tgt - cum; }
    cum += a0;
    if (tgt >= cum && tgt < cum + a1) { sh[0] = (u32)(t * 2 + 1); sh[1] = tgt - cum; }
    __syncthreads();
    const u32 b2 = sh[0], tgt2 = sh[1];

    if (t < 64) h3[t] = 0;
    __syncthreads();
    for (u32 i = t; i < n; i += 1024) {
        u32 k = cand[i];
        if (((k >> 6) & 2047u) == b2) atomicAdd(&h3[k & 63u], 1u);
    }
    __syncthreads();
    if (t == 0) {
        u32 c = 0;
        #pragma unroll
        for (int b = 0; b < 64; b++) {
            u32 h = h3[b];
            if (tgt2 >= c && tgt2 < c + h)
                scal[2] = (scal[0] << 17) | (b2 << 6) | (u32)b;   // kth |w| bit pattern
            c += h;
        }
    }
}

// ---------- mask + f32->bf16 conversion ----------
__global__ void convert_w_kernel(const uint4* __restrict__ wb,
                                 u16* __restrict__ w16,
                                 const u32* __restrict__ scal) {
    const u32 kth = scal[2];
    const int nvec = NW / 4;
    const int stride = gridDim.x * blockDim.x;
    for (int i = blockIdx.x * blockDim.x + threadIdx.x; i < nvec; i += stride) {
        uint4 v = wb[i];
        ushort4 o;
        o.x = ((v.x & 0x7fffffffu) >= kth) ? f2bf_rne(__uint_as_float(v.x)) : (u16)0;
        o.y = ((v.y & 0x7fffffffu) >= kth) ? f2bf_rne(__uint_as_float(v.y)) : (u16)0;
        o.z = ((v.z & 0x7fffffffu) >= kth) ? f2bf_rne(__uint_as_float(v.z)) : (u16)0;
        o.w = ((v.w & 0x7fffffffu) >= kth) ? f2bf_rne(__uint_as_float(v.w)) : (u16)0;
        *(ushort4*)&w16[(size_t)i * 4] = o;
    }
}

__global__ void convert_x_kernel(const float4* __restrict__ xb,
                                 u16* __restrict__ x16) {
    const int nvec = (N_TOK * IN_F) / 4;
    const int stride = gridDim.x * blockDim.x;
    for (int i = blockIdx.x * blockDim.x + threadIdx.x; i < nvec; i += stride) {
        float4 v = xb[i];
        ushort4 o;
        o.x = f2bf_rne(v.x);
        o.y = f2bf_rne(v.y);
        o.z = f2bf_rne(v.z);
        o.w = f2bf_rne(v.w);
        *(ushort4*)&x16[(size_t)i * 4] = o;
    }
}

// ---------- 256x256 8-phase bf16 MFMA GEMM (m201-style template) ----------
// C[t,o] = sum_k A[t,k] * B[o,k] + bias[o];  A = x16 [8192][4096], B = w16 [4096][4096]
#define BK 64
#define NT (IN_F / BK)   // 64 K-tiles

#define ASLOT(buf, ks) (((buf) * 2 + (ks)) * 8192)
#define BSLOT(buf, ks) (32768 + ((buf) * 2 + (ks)) * 8192)

#define VMCNT(n) asm volatile("s_waitcnt vmcnt(" #n ")" ::: "memory")
#define LGKM0    asm volatile("s_waitcnt lgkmcnt(0)" ::: "memory")
#define SB0      __builtin_amdgcn_sched_barrier(0)
#define BARR()   __builtin_amdgcn_s_barrier()

__global__ __launch_bounds__(512, 2) void gemm8p(
    const u16* __restrict__ A,
    const u16* __restrict__ B,
    const float* __restrict__ bias,
    float* __restrict__ C) {
    __shared__ u16 lds[65536];   // 128 KiB

    const int tid  = threadIdx.x;
    const int lane = tid & 63;
    const int ln15 = lane & 15;
    const int l16  = lane >> 4;
    const int wv   = tid >> 6;       // 0..7
    const int wr   = wv >> 2;        // 0..1  (M)
    const int wc   = wv & 3;         // 0..3  (N)
    const int wrow = wr * 128;
    const int wcol = wc * 64;

    const int bid = blockIdx.x;
    const int swz = (bid & 7) * 64 + (bid >> 3);
    const int by  = swz >> 4;        // 0..31
    const int bx  = swz & 15;        // 0..15
    const int arow = by * 256;
    const int brow = bx * 256;

    f32x4 acc[8][4];
    #pragma unroll
    for (int m = 0; m < 8; m++)
        #pragma unroll
        for (int n = 0; n < 4; n++)
            acc[m][n] = {0.f, 0.f, 0.f, 0.f};

    #define STAGE(G, rowbase, kt, ks, slot) do {                                        \
        _Pragma("unroll")                                                               \
        for (int i_ = 0; i_ < 2; i_++) {                                                \
            int q_  = tid + i_ * 512;                                                   \
            int r_  = q_ >> 2;                                                          \
            int cs_ = (q_ & 3) ^ ((r_ >> 1) & 3);                                       \
            const u16* src_ = (G) + (size_t)((rowbase) + r_) * IN_F                     \
                              + (kt) * BK + (ks) * 32 + cs_ * 8;                        \
            __builtin_amdgcn_global_load_lds(                                           \
                (const __attribute__((address_space(1))) unsigned int*)src_,            \
                (__attribute__((address_space(3))) unsigned int*)&lds[(slot) + q_ * 8], \
                16, 0, 0);                                                              \
        } } while (0)

    #define READ_A(mh, ks, buf) do {                                                    \
        _Pragma("unroll")                                                               \
        for (int i_ = 0; i_ < 4; i_++) {                                                \
            int row_ = wrow + ((mh) * 4 + i_) * 16 + ln15;                              \
            int cc_  = l16 ^ ((row_ >> 1) & 3);                                         \
            aF[i_] = *(const bf16x8*)&lds[ASLOT(buf, ks) + row_ * 32 + cc_ * 8];        \
        } } while (0)

    #define READ_B(ks, buf) do {                                                       \
        _Pragma("unroll")                                                               \
        for (int i_ = 0; i_ < 4; i_++) {                                                \
            int row_ = wcol + i_ * 16 + ln15;                                           \
            int cc_  = l16 ^ ((row_ >> 1) & 3);                                         \
            bF[i_] = *(const bf16x8*)&lds[BSLOT(buf, ks) + row_ * 32 + cc_ * 8];        \
        } } while (0)

    #define MFMAQ(mh) do {                                                              \
        __builtin_amdgcn_s_setprio(1);                                                  \
        _Pragma("unroll")                                                               \
        for (int i_ = 0; i_ < 4; i_++)                                                  \
            _Pragma("unroll")                                                           \
            for (int n_ = 0; n_ < 4; n_++)                                              \
                acc[(mh) * 4 + i_][n_] = __builtin_amdgcn_mfma_f32_16x16x32_bf16(       \
                    aF[i_], bF[n_], acc[(mh) * 4 + i_][n_], 0, 0, 0);                   \
        __builtin_amdgcn_s_setprio(0);                                                  \
    } while (0)

    STAGE(B, brow, 0, 0, BSLOT(0, 0));
    STAGE(A, arow, 0, 0, ASLOT(0, 0));
    STAGE(B, brow, 0, 1, BSLOT(0, 1));
    STAGE(A, arow, 0, 1, ASLOT(0, 1));
    VMCNT(4);
    STAGE(B, brow, 1, 0, BSLOT(1, 0));
    STAGE(A, arow, 1, 0, ASLOT(1, 0));
    STAGE(B, brow, 1, 1, BSLOT(1, 1));
    VMCNT(6);
    BARR();

    bf16x8 aF[4], bF[4];

    #pragma unroll 1
    for (int it = 0; it < NT / 2; it++) {
        const int t0 = 2 * it;
        const int ka = t0 + 1;
        const int kb = (t0 + 2 < NT) ? t0 + 2 : NT - 1;
        const int kc = (t0 + 3 < NT) ? t0 + 3 : NT - 1;

        // ---- tile t0 (buf 0) ----
        READ_A(0, 0, 0); READ_B(0, 0);
        STAGE(A, arow, ka, 1, ASLOT(1, 1));
        BARR(); LGKM0; SB0; MFMAQ(0); SB0; BARR();
        READ_A(1, 0, 0);
        STAGE(B, brow, kb, 0, BSLOT(0, 0));
        BARR(); LGKM0; SB0; MFMAQ(1); SB0; BARR();
        READ_A(0, 1, 0); READ_B(1, 0);
        STAGE(A, arow, kb, 0, ASLOT(0, 0));
        BARR(); LGKM0; SB0; MFMAQ(0); SB0; BARR();
        READ_A(1, 1, 0);
        STAGE(B, brow, kb, 1, BSLOT(0, 1));
        VMCNT(6);
        BARR(); LGKM0; SB0; MFMAQ(1); SB0; BARR();

        // ---- tile t0+1 (buf 1) ----
        READ_A(0, 0, 1); READ_B(0, 1);
        STAGE(A, arow, kb, 1, ASLOT(0, 1));
        BARR(); LGKM0; SB0; MFMAQ(0); SB0; BARR();
        READ_A(1, 0, 1);
        STAGE(B, brow, kc, 0, BSLOT(1, 0));
        BARR(); LGKM0; SB0; MFMAQ(1); SB0; BARR();
        READ_A(0, 1, 1); READ_B(1, 1);
        STAGE(A, arow, kc, 0, ASLOT(1, 0));
        BARR(); LGKM0; SB0; MFMAQ(0); SB0; BARR();
        READ_A(1, 1, 1);
        STAGE(B, brow, kc, 1, BSLOT(1, 1));
        VMCNT(6);
        BARR(); LGKM0; SB0; MFMAQ(1); SB0; BARR();
    }
    VMCNT(0);

    const int cr = l16 * 4;
    #pragma unroll
    for (int n = 0; n < 4; n++) {
        int col = brow + wcol + n * 16 + ln15;
        float bv = bias[col];
        #pragma unroll
        for (int m = 0; m < 8; m++) {
            int r0 = arow + wrow + m * 16 + cr;
            #pragma unroll
            for (int j = 0; j < 4; j++) {
                C[(size_t)(r0 + j) * OUT_F + col] = acc[m][n][j] + bv;
            }
        }
    }
}

// ---------- launch ----------
extern "C" void kernel_launch(void* const* d_in, const int* in_sizes, int n_in,
                              void* d_out, int out_size, void* d_ws, size_t ws_size,
                              hipStream_t stream) {
    const float* x    = (const float*)d_in[0];
    const float* w    = (const float*)d_in[1];
    const float* bias = (const float*)d_in[2];
    float* out = (float*)d_out;

    char* ws = (char*)d_ws;
    u32* scal  = (u32*)(ws + 0);                             // 16 u32: [0]=prefix [1]=rem [2]=kth [3]=cand count
    u16* w16   = (u16*)(ws + 65536);                         // 33.5 MB
    u16* x16   = (u16*)(ws + 65536 + (size_t)NW * 2);        // 67 MB
    // hist + cand overlap the x16 region (consumed before convert_x writes it)
    u32* hist16k = (u32*)x16;                                // 64 KB
    u32* cand    = (u32*)((char*)x16 + 131072);              // 4 MB

    hipMemsetAsync(scal, 0, 64, stream);
    hipMemsetAsync(hist16k, 0, 65536, stream);

    hist1_kernel<<<256, 1024, 0, stream>>>((const uint4*)w, hist16k);
    find1_kernel<<<1, 1024, 0, stream>>>(hist16k, scal);
    compact_kernel<<<4096, 256, 0, stream>>>((const uint4*)w, cand, scal);
    select3_kernel<<<1, 1024, 0, stream>>>(cand, scal);

    convert_w_kernel<<<2048, 256, 0, stream>>>((const uint4*)w, w16, scal);
    convert_x_kernel<<<2048, 256, 0, stream>>>((const float4*)x, x16);

    gemm8p<<<512, 512, 0, stream>>>(x16, w16, bias, out);
}